// Round 1
// baseline (460.234 us; speedup 1.0000x reference)
//
#include <hip/hip_runtime.h>

// ---- problem constants ----
#define S_    2048
#define B_    16
#define H2_   1024
#define H_    512
#define N_    4096
#define T_    8192
#define L_    256
#define V_    50000
#define VPAD_ 50048   // 391 * 128

typedef float  floatx4 __attribute__((ext_vector_type(4)));
typedef __bf16 bf16x8  __attribute__((ext_vector_type(8)));

__device__ inline unsigned short f2bf(float f) {
  unsigned u = __builtin_bit_cast(unsigned, f);
  unsigned r = u + 0x7fffu + ((u >> 16) & 1u);   // RNE
  return (unsigned short)(r >> 16);
}
__device__ inline float bf2f(unsigned short s) {
  unsigned u = ((unsigned)s) << 16;
  return __builtin_bit_cast(float, u);
}

// async global->LDS, 16B per lane; LDS dest = wave-uniform base + lane*16
__device__ inline void stage16(const unsigned short* g, unsigned short* l) {
  __builtin_amdgcn_global_load_lds(
      (const __attribute__((address_space(1))) void*)g,
      (__attribute__((address_space(3))) void*)l, 16, 0, 0);
}

// ---- zero scratch accumulators ----
__global__ __launch_bounds__(256) void zero_k(float* __restrict__ p, int n) {
  int i = blockIdx.x * 256 + threadIdx.x;
  if (i < n) p[i] = 0.f;
}

// ---- gather span features -> bf16 [N_][H2_] ----
__global__ __launch_bounds__(256) void gather_k(
    const float* __restrict__ hidden, const int* __restrict__ sbid,
    const int* __restrict__ sbeg, const int* __restrict__ send,
    unsigned short* __restrict__ featbf) {
  const int n = blockIdx.x;
  const int bid = sbid[n];
  int r = sbeg[n] - 1; if (r < 0) r += S_;     // (span_begin-1) mod S
  const int e = send[n];
  const size_t fbase = (size_t)r * (B_ * H2_) + (size_t)bid * H2_;
  const size_t bbase = (size_t)e * (B_ * H2_) + (size_t)bid * H2_;
  unsigned short* out = featbf + (size_t)n * H2_;
  for (int h = threadIdx.x; h < H2_; h += 256) {
    float v = (h < H_) ? hidden[fbase + h] : hidden[bbase + h];
    out[h] = f2bf(v);
  }
}

// ---- convert W1, W2 (padded), b2 (padded) ----
__global__ __launch_bounds__(256) void convert_k(
    const float* __restrict__ W1, const float* __restrict__ W2,
    const float* __restrict__ b2, unsigned short* __restrict__ w1b,
    unsigned short* __restrict__ w2b, float* __restrict__ b2p) {
  const int gid = blockIdx.x * 256 + threadIdx.x;
  const int gstride = gridDim.x * 256;
  for (long j = (long)gid * 8; j < (long)VPAD_ * 256; j += (long)gstride * 8) {
    int row = (int)(j >> 8);
    unsigned short o[8];
    if (row < V_) {
#pragma unroll
      for (int q = 0; q < 8; q++) o[q] = f2bf(W2[j + q]);
    } else {
#pragma unroll
      for (int q = 0; q < 8; q++) o[q] = 0;
    }
    // 16B store
    *reinterpret_cast<ulonglong2*>(w2b + j) = *reinterpret_cast<ulonglong2*>(o);
  }
  for (int j = gid; j < L_ * H2_; j += gstride) w1b[j] = f2bf(W1[j]);
  for (int j = gid; j < VPAD_; j += gstride) b2p[j] = (j < V_) ? b2[j] : -1e30f;
}

// ---- GEMM1: x = tanh(feat @ W1^T + b1), output bf16 [N_][L_] ----
__global__ __launch_bounds__(256) void gemm1_k(
    const unsigned short* __restrict__ A,   // featbf [N_][H2_]
    const unsigned short* __restrict__ Bw,  // w1bf  [L_][H2_]
    const float* __restrict__ b1,
    unsigned short* __restrict__ xbf) {     // [N_][L_]
  __shared__ unsigned short sA[128 * 32];
  __shared__ unsigned short sB[128 * 32];
  const int tid   = threadIdx.x;
  const int mtile = (int)(blockIdx.x >> 1) * 128;
  const int ntile = (int)(blockIdx.x & 1) * 128;
  const int lane = tid & 63, wave = tid >> 6;
  const int wr = (wave >> 1) * 64, wc = (wave & 1) * 64;
  const int fr = lane & 15, fq = lane >> 4;
  floatx4 acc[4][4] = {};
  const int srow = tid >> 2, skg = (tid & 3) * 8;
  const unsigned short* gA0 = A  + (size_t)(mtile + srow) * H2_ + skg;
  const unsigned short* gA1 = A  + (size_t)(mtile + 64 + srow) * H2_ + skg;
  const unsigned short* gB0 = Bw + (size_t)(ntile + srow) * H2_ + skg;
  const unsigned short* gB1 = Bw + (size_t)(ntile + 64 + srow) * H2_ + skg;
  unsigned short* lA = sA + tid * 8;
  unsigned short* lB = sB + tid * 8;
  for (int k0 = 0; k0 < H2_; k0 += 32) {
    stage16(gA0 + k0, lA);
    stage16(gA1 + k0, lA + 2048);
    stage16(gB0 + k0, lB);
    stage16(gB1 + k0, lB + 2048);
    __syncthreads();
    bf16x8 av[4], bv[4];
#pragma unroll
    for (int mi = 0; mi < 4; mi++)
      av[mi] = *reinterpret_cast<const bf16x8*>(sA + (wr + mi * 16 + fr) * 32 + fq * 8);
#pragma unroll
    for (int ni = 0; ni < 4; ni++)
      bv[ni] = *reinterpret_cast<const bf16x8*>(sB + (wc + ni * 16 + fr) * 32 + fq * 8);
#pragma unroll
    for (int mi = 0; mi < 4; mi++)
#pragma unroll
      for (int ni = 0; ni < 4; ni++)
        acc[mi][ni] = __builtin_amdgcn_mfma_f32_16x16x32_bf16(av[mi], bv[ni], acc[mi][ni], 0, 0, 0);
    __syncthreads();
  }
#pragma unroll
  for (int ni = 0; ni < 4; ni++) {
    const int col = ntile + wc + ni * 16 + fr;
    const float bias = b1[col];
#pragma unroll
    for (int mi = 0; mi < 4; mi++)
#pragma unroll
      for (int r = 0; r < 4; r++) {
        const int row = mtile + wr + mi * 16 + fq * 4 + r;
        xbf[(size_t)row * L_ + col] = f2bf(tanhf(acc[mi][ni][r] + bias));
      }
  }
}

// ---- GEMM2 + online sum-of-exp: atomicAdd per-row partial sums ----
__global__ __launch_bounds__(256) void gemm2_k(
    const unsigned short* __restrict__ X,   // xbf [N_][L_]
    const unsigned short* __restrict__ Wb,  // w2bf [VPAD_][L_]
    const float* __restrict__ b2p,          // [VPAD_] (-1e30 on pad)
    float* __restrict__ lse_sum) {          // [N_], pre-zeroed
  __shared__ unsigned short sA[128 * 32];
  __shared__ unsigned short sB[128 * 32];
  const int tid   = threadIdx.x;
  const int mtile = (int)(blockIdx.x & 31) * 128;
  const int vtile = (int)(blockIdx.x >> 5) * 128;
  const int lane = tid & 63, wave = tid >> 6;
  const int wr = (wave >> 1) * 64, wc = (wave & 1) * 64;
  const int fr = lane & 15, fq = lane >> 4;
  floatx4 acc[4][4] = {};
  const int srow = tid >> 2, skg = (tid & 3) * 8;
  const unsigned short* gA0 = X  + (size_t)(mtile + srow) * L_ + skg;
  const unsigned short* gA1 = X  + (size_t)(mtile + 64 + srow) * L_ + skg;
  const unsigned short* gB0 = Wb + (size_t)(vtile + srow) * L_ + skg;
  const unsigned short* gB1 = Wb + (size_t)(vtile + 64 + srow) * L_ + skg;
  unsigned short* lA = sA + tid * 8;
  unsigned short* lB = sB + tid * 8;
  for (int k0 = 0; k0 < L_; k0 += 32) {
    stage16(gA0 + k0, lA);
    stage16(gA1 + k0, lA + 2048);
    stage16(gB0 + k0, lB);
    stage16(gB1 + k0, lB + 2048);
    __syncthreads();
    bf16x8 av[4], bv[4];
#pragma unroll
    for (int mi = 0; mi < 4; mi++)
      av[mi] = *reinterpret_cast<const bf16x8*>(sA + (wr + mi * 16 + fr) * 32 + fq * 8);
#pragma unroll
    for (int ni = 0; ni < 4; ni++)
      bv[ni] = *reinterpret_cast<const bf16x8*>(sB + (wc + ni * 16 + fr) * 32 + fq * 8);
#pragma unroll
    for (int mi = 0; mi < 4; mi++)
#pragma unroll
      for (int ni = 0; ni < 4; ni++)
        acc[mi][ni] = __builtin_amdgcn_mfma_f32_16x16x32_bf16(av[mi], bv[ni], acc[mi][ni], 0, 0, 0);
    __syncthreads();
  }
  // epilogue: exp(logit + b2) -> per-row sum over this block's 128 cols
  float bias[4];
#pragma unroll
  for (int ni = 0; ni < 4; ni++) bias[ni] = b2p[vtile + wc + ni * 16 + fr];
#pragma unroll
  for (int mi = 0; mi < 4; mi++) {
#pragma unroll
    for (int r = 0; r < 4; r++) {
      float s = 0.f;
#pragma unroll
      for (int ni = 0; ni < 4; ni++)
        s += __expf(acc[mi][ni][r] + bias[ni]);
      s += __shfl_xor(s, 1);
      s += __shfl_xor(s, 2);
      s += __shfl_xor(s, 4);
      s += __shfl_xor(s, 8);    // sum across the 16 cols held by this lane group
      if (fr == 0)
        atomicAdd(&lse_sum[mtile + wr + mi * 16 + fq * 4 + r], s);
    }
  }
}

// ---- focal loss over T tags: one wave per tag ----
__global__ __launch_bounds__(256) void loss_k(
    const unsigned short* __restrict__ xbf, const float* __restrict__ W2,
    const float* __restrict__ b2, const int* __restrict__ tsid,
    const int* __restrict__ tags, const float* __restrict__ lse_sum,
    float* __restrict__ loss_acc) {
  const int lane = threadIdx.x & 63;
  const int gw = (int)(blockIdx.x * 256 + threadIdx.x) >> 6;
  const int nw = (int)(gridDim.x * 256) >> 6;
  float total = 0.f;
  for (int t = gw; t < T_; t += nw) {
    const int sid = tsid[t];
    const int v   = tags[t];
    const unsigned short* xr = xbf + (size_t)sid * L_;
    const float* w2r = W2 + (size_t)v * L_;
    float d = 0.f;
#pragma unroll
    for (int q = 0; q < 4; q++) {
      const int j = lane * 4 + q;
      d += bf2f(xr[j]) * w2r[j];
    }
#pragma unroll
    for (int m = 1; m < 64; m <<= 1) d += __shfl_xor(d, m);
    const float lp  = d + b2[v] - logf(lse_sum[sid]);
    const float pos = __expf(lp);
    total += (pos - 1.f) * lp;   // == -(1-pos)^1 * lp
  }
  if (lane == 0) atomicAdd(loss_acc, total);
}

__global__ void final_k(const float* __restrict__ loss_acc, float* __restrict__ out) {
  if (threadIdx.x == 0) out[0] = loss_acc[0] / (8192.0f + 1e-5f);
}

// ---- host launcher ----
extern "C" void kernel_launch(void* const* d_in, const int* in_sizes, int n_in,
                              void* d_out, int out_size, void* d_ws, size_t ws_size,
                              hipStream_t stream) {
  const float* hidden = (const float*)d_in[0];
  const float* W1     = (const float*)d_in[1];
  const float* b1     = (const float*)d_in[2];
  const float* W2     = (const float*)d_in[3];
  const float* b2     = (const float*)d_in[4];
  const int* sbid = (const int*)d_in[5];
  const int* sbeg = (const int*)d_in[6];
  const int* send = (const int*)d_in[7];
  const int* tsid = (const int*)d_in[8];
  const int* tags = (const int*)d_in[9];
  float* out = (float*)d_out;

  char* ws = (char*)d_ws;
  // ws layout (all 16B aligned)
  unsigned short* featbf = (unsigned short*)(ws);              //  8,388,608 B
  unsigned short* xbf    = (unsigned short*)(ws + 8388608);    //  2,097,152 B
  unsigned short* w1bf   = (unsigned short*)(ws + 10485760);   //    524,288 B
  unsigned short* w2bf   = (unsigned short*)(ws + 11010048);   // 25,624,576 B
  float* b2p  = (float*)(ws + 36634624);                       //    200,192 B
  float* lse  = (float*)(ws + 36834816);                       //     16,384 B
  float* lacc = (float*)(ws + 36851200);                       //          4 B

  zero_k<<<dim3(17), dim3(256), 0, stream>>>(lse, N_ + 1);   // lse + loss_acc (contiguous)
  gather_k<<<dim3(N_), dim3(256), 0, stream>>>(hidden, sbid, sbeg, send, featbf);
  convert_k<<<dim3(2048), dim3(256), 0, stream>>>(W1, W2, b2, w1bf, w2bf, b2p);
  gemm1_k<<<dim3(64), dim3(256), 0, stream>>>(featbf, w1bf, b1, xbf);
  gemm2_k<<<dim3((VPAD_ / 128) * (N_ / 128)), dim3(256), 0, stream>>>(xbf, w2bf, b2p, lse);
  loss_k<<<dim3(64), dim3(256), 0, stream>>>(xbf, W2, b2, tsid, tags, lse, lacc);
  final_k<<<dim3(1), dim3(64), 0, stream>>>(lacc, out);
}

// Round 2
// 394.663 us; speedup vs baseline: 1.1661x; 1.1661x over previous
//
#include <hip/hip_runtime.h>

// ---- problem constants ----
#define S_    2048
#define B_    16
#define H2_   1024
#define H_    512
#define N_    4096
#define T_    8192
#define L_    256
#define V_    50000
#define VPAD_ 50048   // 391 * 128

typedef float  floatx4 __attribute__((ext_vector_type(4)));
typedef __bf16 bf16x8  __attribute__((ext_vector_type(8)));

__device__ inline unsigned short f2bf(float f) {
  unsigned u = __builtin_bit_cast(unsigned, f);
  unsigned r = u + 0x7fffu + ((u >> 16) & 1u);   // RNE
  return (unsigned short)(r >> 16);
}
__device__ inline float bf2f(unsigned short s) {
  unsigned u = ((unsigned)s) << 16;
  return __builtin_bit_cast(float, u);
}

// async global->LDS, 16B per lane; LDS dest = wave-uniform base + lane*16
__device__ inline void stage16(const unsigned short* g, unsigned short* l) {
  __builtin_amdgcn_global_load_lds(
      (const __attribute__((address_space(1))) void*)g,
      (__attribute__((address_space(3))) void*)l, 16, 0, 0);
}

// ---- zero scratch accumulators ----
__global__ __launch_bounds__(256) void zero_k(float* __restrict__ p, int n) {
  int i = blockIdx.x * 256 + threadIdx.x;
  if (i < n) p[i] = 0.f;
}

// ---- gather span features -> bf16 [N_][H2_] ----
__global__ __launch_bounds__(256) void gather_k(
    const float* __restrict__ hidden, const int* __restrict__ sbid,
    const int* __restrict__ sbeg, const int* __restrict__ send,
    unsigned short* __restrict__ featbf) {
  const int n = blockIdx.x;
  const int bid = sbid[n];
  int r = sbeg[n] - 1; if (r < 0) r += S_;     // (span_begin-1) mod S
  const int e = send[n];
  const size_t fbase = (size_t)r * (B_ * H2_) + (size_t)bid * H2_;
  const size_t bbase = (size_t)e * (B_ * H2_) + (size_t)bid * H2_;
  unsigned short* out = featbf + (size_t)n * H2_;
  for (int h = threadIdx.x; h < H2_; h += 256) {
    float v = (h < H_) ? hidden[fbase + h] : hidden[bbase + h];
    out[h] = f2bf(v);
  }
}

// ---- convert W1, W2 (padded), b2 (padded) ----
__global__ __launch_bounds__(256) void convert_k(
    const float* __restrict__ W1, const float* __restrict__ W2,
    const float* __restrict__ b2, unsigned short* __restrict__ w1b,
    unsigned short* __restrict__ w2b, float* __restrict__ b2p) {
  const int gid = blockIdx.x * 256 + threadIdx.x;
  const int gstride = gridDim.x * 256;
  for (long j = (long)gid * 8; j < (long)VPAD_ * 256; j += (long)gstride * 8) {
    int row = (int)(j >> 8);
    unsigned short o[8];
    if (row < V_) {
#pragma unroll
      for (int q = 0; q < 8; q++) o[q] = f2bf(W2[j + q]);
    } else {
#pragma unroll
      for (int q = 0; q < 8; q++) o[q] = 0;
    }
    *reinterpret_cast<ulonglong2*>(w2b + j) = *reinterpret_cast<ulonglong2*>(o);
  }
  for (int j = gid; j < L_ * H2_; j += gstride) w1b[j] = f2bf(W1[j]);
  for (int j = gid; j < VPAD_; j += gstride) b2p[j] = (j < V_) ? b2[j] : -1e30f;
}

// ---- GEMM1: x = tanh(feat @ W1^T + b1), output bf16 [N_][L_] ----
__global__ __launch_bounds__(256) void gemm1_k(
    const unsigned short* __restrict__ A,   // featbf [N_][H2_]
    const unsigned short* __restrict__ Bw,  // w1bf  [L_][H2_]
    const float* __restrict__ b1,
    unsigned short* __restrict__ xbf) {     // [N_][L_]
  __shared__ unsigned short sA[128 * 32];
  __shared__ unsigned short sB[128 * 32];
  const int tid   = threadIdx.x;
  const int mtile = (int)(blockIdx.x >> 1) * 128;
  const int ntile = (int)(blockIdx.x & 1) * 128;
  const int lane = tid & 63, wave = tid >> 6;
  const int wr = (wave >> 1) * 64, wc = (wave & 1) * 64;
  const int fr = lane & 15, fq = lane >> 4;
  floatx4 acc[4][4] = {};
  const int srow = tid >> 2, skg = (tid & 3) * 8;
  const unsigned short* gA0 = A  + (size_t)(mtile + srow) * H2_ + skg;
  const unsigned short* gA1 = A  + (size_t)(mtile + 64 + srow) * H2_ + skg;
  const unsigned short* gB0 = Bw + (size_t)(ntile + srow) * H2_ + skg;
  const unsigned short* gB1 = Bw + (size_t)(ntile + 64 + srow) * H2_ + skg;
  unsigned short* lA = sA + tid * 8;
  unsigned short* lB = sB + tid * 8;
  for (int k0 = 0; k0 < H2_; k0 += 32) {
    stage16(gA0 + k0, lA);
    stage16(gA1 + k0, lA + 2048);
    stage16(gB0 + k0, lB);
    stage16(gB1 + k0, lB + 2048);
    __syncthreads();
    bf16x8 av[4], bv[4];
#pragma unroll
    for (int mi = 0; mi < 4; mi++)
      av[mi] = *reinterpret_cast<const bf16x8*>(sA + (wr + mi * 16 + fr) * 32 + fq * 8);
#pragma unroll
    for (int ni = 0; ni < 4; ni++)
      bv[ni] = *reinterpret_cast<const bf16x8*>(sB + (wc + ni * 16 + fr) * 32 + fq * 8);
#pragma unroll
    for (int mi = 0; mi < 4; mi++)
#pragma unroll
      for (int ni = 0; ni < 4; ni++)
        acc[mi][ni] = __builtin_amdgcn_mfma_f32_16x16x32_bf16(av[mi], bv[ni], acc[mi][ni], 0, 0, 0);
    __syncthreads();
  }
#pragma unroll
  for (int ni = 0; ni < 4; ni++) {
    const int col = ntile + wc + ni * 16 + fr;
    const float bias = b1[col];
#pragma unroll
    for (int mi = 0; mi < 4; mi++)
#pragma unroll
      for (int r = 0; r < 4; r++) {
        const int row = mtile + wr + mi * 16 + fq * 4 + r;
        xbf[(size_t)row * L_ + col] = f2bf(tanhf(acc[mi][ni][r] + bias));
      }
  }
}

// ---- GEMM2 + online sum-of-exp ----
// A (X tile) register-resident; B (W2) double-buffered full-K LDS tiles with
// async prefetch guarded by s_waitcnt vmcnt(20) (never 0). XOR chunk swizzle
// applied on the GLOBAL source address (LDS dest of global_load_lds is
// lane-fixed) so frag ds_read_b128 hits distinct bank spans.
// Grid: 32 mtiles x 16 v-strips = 512 blocks; 1 block/CU (128KB LDS), 2 rounds.
__global__ __launch_bounds__(256, 1) void gemm2_k(
    const unsigned short* __restrict__ X,   // xbf [N_][L_]
    const unsigned short* __restrict__ Wb,  // w2bf [VPAD_][L_]
    const float* __restrict__ b2p,          // [VPAD_] (-1e30 on pad)
    float* __restrict__ lse_sum) {          // [N_], pre-zeroed
  __shared__ __align__(16) unsigned short sB[2][128 * 256];  // 2 x 64KB
  const int tid   = threadIdx.x;
  const int mtile = ((int)blockIdx.x & 31) * 128;
  const int strip = (int)blockIdx.x >> 5;                    // 0..15
  const int vt0   = (strip < 7) ? strip * 25 : 175 + (strip - 7) * 24;
  const int nt    = (strip < 7) ? 25 : 24;                   // 7*25+9*24=391
  const int lane = tid & 63, wave = tid >> 6;
  const int wr = (wave >> 1) * 64, wc = (wave & 1) * 64;
  const int fr = lane & 15, fq = lane >> 4;

  // ---- stage A tile (swizzled) into sB[0], pull frags to registers ----
#pragma unroll
  for (int i = 0; i < 16; i++) {
    const int slot = tid + i * 256;           // 0..4095 (16B chunks)
    const int r = slot >> 5, kcp = slot & 31;
    const int kc = (kcp & 24) | ((kcp ^ r) & 7);
    stage16(X + (size_t)(mtile + r) * 256 + kc * 8, &sB[0][slot * 8]);
  }
  __syncthreads();
  bf16x8 af[4][8];
#pragma unroll
  for (int mi = 0; mi < 4; mi++)
#pragma unroll
    for (int ks = 0; ks < 8; ks++) {
      const int r = wr + mi * 16 + fr;
      const int kc = ks * 4 + fq;
      const int slot = (r << 5) | (kc & 24) | ((kc ^ r) & 7);
      af[mi][ks] = *reinterpret_cast<const bf16x8*>(&sB[0][slot * 8]);
    }
  __syncthreads();   // all waves done with A before buf0 is reused for B

  float sacc[4][4];
#pragma unroll
  for (int mi = 0; mi < 4; mi++)
#pragma unroll
    for (int r = 0; r < 4; r++) sacc[mi][r] = 0.f;

  // prologue: bias + stage for tile 0
  float bias_nxt[4], bias_cur[4];
#pragma unroll
  for (int ni = 0; ni < 4; ni++)
    bias_nxt[ni] = b2p[vt0 * 128 + wc + ni * 16 + fr];
  {
    const unsigned short* base = Wb + (size_t)vt0 * 128 * 256;
#pragma unroll
    for (int i = 0; i < 16; i++) {
      const int slot = tid + i * 256;
      const int r = slot >> 5, kcp = slot & 31;
      const int kc = (kcp & 24) | ((kcp ^ r) & 7);
      stage16(base + (size_t)r * 256 + kc * 8, &sB[0][slot * 8]);
    }
  }

  for (int j = 0; j < nt; j++) {
#pragma unroll
    for (int ni = 0; ni < 4; ni++) bias_cur[ni] = bias_nxt[ni];
    if (j + 1 < nt) {
      const int vt = vt0 + j + 1;
#pragma unroll
      for (int ni = 0; ni < 4; ni++)
        bias_nxt[ni] = b2p[vt * 128 + wc + ni * 16 + fr];
      const unsigned short* base = Wb + (size_t)vt * 128 * 256;
      unsigned short* dst = &sB[(j + 1) & 1][0];
#pragma unroll
      for (int i = 0; i < 16; i++) {
        const int slot = tid + i * 256;
        const int r = slot >> 5, kcp = slot & 31;
        const int kc = (kcp & 24) | ((kcp ^ r) & 7);
        stage16(base + (size_t)r * 256 + kc * 8, dst + slot * 8);
      }
      // wait until only the newest 20 vm ops (bias j+1 + stage j+1) remain
      __builtin_amdgcn_s_waitcnt(0x4F74);   // vmcnt(20), exp/lgkm no-wait
    } else {
      __builtin_amdgcn_s_waitcnt(0x0F70);   // vmcnt(0)
    }
    __builtin_amdgcn_s_barrier();

    const unsigned short* bb = &sB[j & 1][0];
    floatx4 acc[4][4] = {};
#pragma unroll
    for (int ks = 0; ks < 8; ks++) {
      bf16x8 bv[4];
#pragma unroll
      for (int ni = 0; ni < 4; ni++) {
        const int r = wc + ni * 16 + fr;
        const int kc = ks * 4 + fq;
        const int slot = (r << 5) | (kc & 24) | ((kc ^ r) & 7);
        bv[ni] = *reinterpret_cast<const bf16x8*>(&bb[slot * 8]);
      }
#pragma unroll
      for (int mi = 0; mi < 4; mi++)
#pragma unroll
        for (int ni = 0; ni < 4; ni++)
          acc[mi][ni] = __builtin_amdgcn_mfma_f32_16x16x32_bf16(af[mi][ks], bv[ni], acc[mi][ni], 0, 0, 0);
    }
    // epilogue: accumulate sum of exp locally (no atomics here)
#pragma unroll
    for (int mi = 0; mi < 4; mi++)
#pragma unroll
      for (int r = 0; r < 4; r++) {
        float s = sacc[mi][r];
#pragma unroll
        for (int ni = 0; ni < 4; ni++)
          s += __expf(acc[mi][ni][r] + bias_cur[ni]);
        sacc[mi][r] = s;
      }
    // single barrier/iter: passing iter j+1's barrier implies all waves
    // finished computing on buf[j&1] before iter j+2 overwrites it.
  }

  // final reduction: sum across the 16 fr lanes, one atomic per row
#pragma unroll
  for (int mi = 0; mi < 4; mi++)
#pragma unroll
    for (int r = 0; r < 4; r++) {
      float s = sacc[mi][r];
      s += __shfl_xor(s, 1);
      s += __shfl_xor(s, 2);
      s += __shfl_xor(s, 4);
      s += __shfl_xor(s, 8);
      if (fr == 0)
        atomicAdd(&lse_sum[mtile + wr + mi * 16 + fq * 4 + r], s);
    }
}

// ---- focal loss over T tags: one wave per tag-group ----
__global__ __launch_bounds__(256) void loss_k(
    const unsigned short* __restrict__ xbf, const float* __restrict__ W2,
    const float* __restrict__ b2, const int* __restrict__ tsid,
    const int* __restrict__ tags, const float* __restrict__ lse_sum,
    float* __restrict__ loss_acc) {
  const int lane = threadIdx.x & 63;
  const int gw = (int)(blockIdx.x * 256 + threadIdx.x) >> 6;
  const int nw = (int)(gridDim.x * 256) >> 6;
  float total = 0.f;
  for (int t = gw; t < T_; t += nw) {
    const int sid = tsid[t];
    const int v   = tags[t];
    const unsigned short* xr = xbf + (size_t)sid * L_;
    const float* w2r = W2 + (size_t)v * L_;
    float d = 0.f;
#pragma unroll
    for (int q = 0; q < 4; q++) {
      const int j = lane * 4 + q;
      d += bf2f(xr[j]) * w2r[j];
    }
#pragma unroll
    for (int m = 1; m < 64; m <<= 1) d += __shfl_xor(d, m);
    const float lp  = d + b2[v] - logf(lse_sum[sid]);
    const float pos = __expf(lp);
    total += (pos - 1.f) * lp;   // == -(1-pos)^1 * lp
  }
  if (lane == 0) atomicAdd(loss_acc, total);
}

__global__ void final_k(const float* __restrict__ loss_acc, float* __restrict__ out) {
  if (threadIdx.x == 0) out[0] = loss_acc[0] / (8192.0f + 1e-5f);
}

// ---- host launcher ----
extern "C" void kernel_launch(void* const* d_in, const int* in_sizes, int n_in,
                              void* d_out, int out_size, void* d_ws, size_t ws_size,
                              hipStream_t stream) {
  const float* hidden = (const float*)d_in[0];
  const float* W1     = (const float*)d_in[1];
  const float* b1     = (const float*)d_in[2];
  const float* W2     = (const float*)d_in[3];
  const float* b2     = (const float*)d_in[4];
  const int* sbid = (const int*)d_in[5];
  const int* sbeg = (const int*)d_in[6];
  const int* send = (const int*)d_in[7];
  const int* tsid = (const int*)d_in[8];
  const int* tags = (const int*)d_in[9];
  float* out = (float*)d_out;

  char* ws = (char*)d_ws;
  unsigned short* featbf = (unsigned short*)(ws);              //  8,388,608 B
  unsigned short* xbf    = (unsigned short*)(ws + 8388608);    //  2,097,152 B
  unsigned short* w1bf   = (unsigned short*)(ws + 10485760);   //    524,288 B
  unsigned short* w2bf   = (unsigned short*)(ws + 11010048);   // 25,624,576 B
  float* b2p  = (float*)(ws + 36634624);                       //    200,192 B
  float* lse  = (float*)(ws + 36834816);                       //     16,384 B
  float* lacc = (float*)(ws + 36851200);                       //          4 B

  zero_k<<<dim3(17), dim3(256), 0, stream>>>(lse, N_ + 1);   // lse + loss_acc
  gather_k<<<dim3(N_), dim3(256), 0, stream>>>(hidden, sbid, sbeg, send, featbf);
  convert_k<<<dim3(2048), dim3(256), 0, stream>>>(W1, W2, b2, w1bf, w2bf, b2p);
  gemm1_k<<<dim3(64), dim3(256), 0, stream>>>(featbf, w1bf, b1, xbf);
  gemm2_k<<<dim3(512), dim3(256), 0, stream>>>(xbf, w2bf, b2p, lse);
  loss_k<<<dim3(256), dim3(256), 0, stream>>>(xbf, W2, b2, tsid, tags, lse, lacc);
  final_k<<<dim3(1), dim3(64), 0, stream>>>(lacc, out);
}

// Round 3
// 366.300 us; speedup vs baseline: 1.2564x; 1.0774x over previous
//
#include <hip/hip_runtime.h>

// ---- problem constants ----
#define S_    2048
#define B_    16
#define H2_   1024
#define H_    512
#define N_    4096
#define T_    8192
#define L_    256
#define V_    50000
#define VPAD_ 50048   // 391 * 128

typedef float  floatx4 __attribute__((ext_vector_type(4)));
typedef __bf16 bf16x8  __attribute__((ext_vector_type(8)));

__device__ inline unsigned short f2bf(float f) {
  unsigned u = __builtin_bit_cast(unsigned, f);
  unsigned r = u + 0x7fffu + ((u >> 16) & 1u);   // RNE
  return (unsigned short)(r >> 16);
}
__device__ inline float bf2f(unsigned short s) {
  unsigned u = ((unsigned)s) << 16;
  return __builtin_bit_cast(float, u);
}

// async global->LDS, 16B per lane; LDS dest = wave-uniform base + lane*16
__device__ inline void stage16(const unsigned short* g, unsigned short* l) {
  __builtin_amdgcn_global_load_lds(
      (const __attribute__((address_space(1))) void*)g,
      (__attribute__((address_space(3))) void*)l, 16, 0, 0);
}

// ---- gather span features -> bf16 [N_][H2_]; also zeroes lse/loss accumulators ----
__global__ __launch_bounds__(256) void gather_k(
    const float* __restrict__ hidden, const int* __restrict__ sbid,
    const int* __restrict__ sbeg, const int* __restrict__ send,
    unsigned short* __restrict__ featbf, float* __restrict__ lse) {
  const int n = blockIdx.x;
  const int t = threadIdx.x;
  if (t == 0) lse[n] = 0.f;
  if (n == 0 && t == 1) lse[N_] = 0.f;   // loss accumulator lives at lse[N_]
  const int bid = sbid[n];
  int r = sbeg[n] - 1; if (r < 0) r += S_;     // (span_begin-1) mod S
  const int e = send[n];
  const size_t fbase = (size_t)r * (B_ * H2_) + (size_t)bid * H2_;
  const size_t bbase = (size_t)e * (B_ * H2_) + (size_t)bid * H2_;
  const int c = t * 4;                    // element index 0..1023 (wave-uniform branch)
  const float4 v = (t < 128) ? *reinterpret_cast<const float4*>(hidden + fbase + c)
                             : *reinterpret_cast<const float4*>(hidden + bbase + c);
  unsigned short o[4];
  o[0] = f2bf(v.x); o[1] = f2bf(v.y); o[2] = f2bf(v.z); o[3] = f2bf(v.w);
  *reinterpret_cast<unsigned long long*>(featbf + (size_t)n * H2_ + c) =
      *reinterpret_cast<unsigned long long*>(o);
}

// ---- convert W1, W2 (padded), b2 (padded) ----
__global__ __launch_bounds__(256) void convert_k(
    const float* __restrict__ W1, const float* __restrict__ W2,
    const float* __restrict__ b2, unsigned short* __restrict__ w1b,
    unsigned short* __restrict__ w2b, float* __restrict__ b2p) {
  const int gid = blockIdx.x * 256 + threadIdx.x;
  const int gstride = gridDim.x * 256;
  for (long j = (long)gid * 8; j < (long)VPAD_ * 256; j += (long)gstride * 8) {
    int row = (int)(j >> 8);
    unsigned short o[8];
    if (row < V_) {
#pragma unroll
      for (int q = 0; q < 8; q++) o[q] = f2bf(W2[j + q]);
    } else {
#pragma unroll
      for (int q = 0; q < 8; q++) o[q] = 0;
    }
    *reinterpret_cast<ulonglong2*>(w2b + j) = *reinterpret_cast<ulonglong2*>(o);
  }
  for (int j = gid; j < L_ * H2_; j += gstride) w1b[j] = f2bf(W1[j]);
  for (int j = gid; j < VPAD_; j += gstride) b2p[j] = (j < V_) ? b2[j] : -1e30f;
}

// ---- GEMM1: x = tanh(feat @ W1^T + b1), 64x64 tiles, 256 blocks ----
__global__ __launch_bounds__(256) void gemm1_k(
    const unsigned short* __restrict__ A,   // featbf [N_][H2_]
    const unsigned short* __restrict__ Bw,  // w1bf  [L_][H2_]
    const float* __restrict__ b1,
    unsigned short* __restrict__ xbf) {     // [N_][L_]
  __shared__ __align__(16) unsigned short sA[64 * 64];
  __shared__ __align__(16) unsigned short sB[64 * 64];
  const int tid   = threadIdx.x;
  const int mtile = (int)(blockIdx.x >> 2) * 64;
  const int ntile = (int)(blockIdx.x & 3) * 64;
  const int lane = tid & 63, wave = tid >> 6;
  const int wr = (wave & 1) * 32, wc = (wave >> 1) * 32;
  const int fr = lane & 15, fq = lane >> 4;
  floatx4 acc[2][2] = {};
  for (int k0 = 0; k0 < H2_; k0 += 64) {
#pragma unroll
    for (int i = 0; i < 2; i++) {
      const int slot = tid + i * 256;          // 0..511 (16B chunks)
      const int r = slot >> 3, cc = slot & 7;
      const int gk = cc ^ (r & 7);             // bank swizzle on global source
      stage16(A  + (size_t)(mtile + r) * H2_ + k0 + gk * 8, &sA[slot * 8]);
      stage16(Bw + (size_t)(ntile + r) * H2_ + k0 + gk * 8, &sB[slot * 8]);
    }
    __syncthreads();
#pragma unroll
    for (int ks = 0; ks < 2; ks++) {
      bf16x8 av[2], bv[2];
#pragma unroll
      for (int mi = 0; mi < 2; mi++) {
        const int r = wr + mi * 16 + fr, kc = ks * 4 + fq;
        av[mi] = *reinterpret_cast<const bf16x8*>(&sA[(r * 8 + (kc ^ (r & 7))) * 8]);
      }
#pragma unroll
      for (int ni = 0; ni < 2; ni++) {
        const int r = wc + ni * 16 + fr, kc = ks * 4 + fq;
        bv[ni] = *reinterpret_cast<const bf16x8*>(&sB[(r * 8 + (kc ^ (r & 7))) * 8]);
      }
#pragma unroll
      for (int mi = 0; mi < 2; mi++)
#pragma unroll
        for (int ni = 0; ni < 2; ni++)
          acc[mi][ni] = __builtin_amdgcn_mfma_f32_16x16x32_bf16(av[mi], bv[ni], acc[mi][ni], 0, 0, 0);
    }
    __syncthreads();
  }
#pragma unroll
  for (int ni = 0; ni < 2; ni++) {
    const int col = ntile + wc + ni * 16 + fr;
    const float bias = b1[col];
#pragma unroll
    for (int mi = 0; mi < 2; mi++)
#pragma unroll
      for (int r = 0; r < 4; r++) {
        const int row = mtile + wr + mi * 16 + fq * 4 + r;
        xbf[(size_t)row * L_ + col] = f2bf(tanhf(acc[mi][ni][r] + bias));
      }
  }
}

// ---- GEMM2 + online sum-of-exp ----
// 512 threads (8 waves, 2 waves/SIMD). A tile register-resident. B double-
// buffered 64KB LDS, async prefetch guarded by s_waitcnt vmcnt(8) (= exactly
// the in-flight stage ops). Raw s_barrier (asm, no drain) closes the
// write-after-read race without killing the in-flight prefetch.
// Grid: 8 strips x 32 mtiles = 256 blocks, 1 block/CU.
__global__ __launch_bounds__(512, 2) void gemm2_k(
    const unsigned short* __restrict__ X,   // xbf [N_][L_]
    const unsigned short* __restrict__ Wb,  // w2bf [VPAD_][L_]
    const float* __restrict__ b2p,          // [VPAD_] (-1e30 on pad)
    float* __restrict__ lse_sum) {          // [N_], pre-zeroed
  __shared__ __align__(16) unsigned short sB[2][128 * 256];  // 2 x 64KB
  const int tid   = threadIdx.x;
  const int mtile = ((int)blockIdx.x & 31) * 128;
  const int strip = (int)blockIdx.x >> 5;                    // 0..7
  const int vt0   = strip * 49;
  const int nt    = (strip < 7) ? 49 : 48;                   // 7*49+48=391
  const int lane = tid & 63, wave = tid >> 6;
  const int wr = (wave & 3) * 32;                            // 4 m-waves
  const int wc = (wave >> 2) * 64;                           // 2 n-waves
  const int fr = lane & 15, fq = lane >> 4;

  // ---- stage A tile (swizzled) into sB[0], pull frags to registers ----
#pragma unroll
  for (int i = 0; i < 8; i++) {
    const int slot = tid + i * 512;           // 0..4095 (16B chunks)
    const int r = slot >> 5, kcp = slot & 31;
    const int kc = (kcp & 24) | ((kcp ^ r) & 7);
    stage16(X + (size_t)(mtile + r) * 256 + kc * 8, &sB[0][slot * 8]);
  }
  __syncthreads();
  bf16x8 af[2][8];
#pragma unroll
  for (int mi = 0; mi < 2; mi++)
#pragma unroll
    for (int ks = 0; ks < 8; ks++) {
      const int r = wr + mi * 16 + fr;
      const int kc = ks * 4 + fq;
      const int slot = (r << 5) | (kc & 24) | ((kc ^ r) & 7);
      af[mi][ks] = *reinterpret_cast<const bf16x8*>(&sB[0][slot * 8]);
    }
  __syncthreads();   // all waves done with A before buf0 is reused for B

  float sacc[2][4];
#pragma unroll
  for (int mi = 0; mi < 2; mi++)
#pragma unroll
    for (int r = 0; r < 4; r++) sacc[mi][r] = 0.f;

  // prologue: bias + stage for tile 0 (into buf0)
  float bias_nxt[4], bias_cur[4];
#pragma unroll
  for (int ni = 0; ni < 4; ni++)
    bias_nxt[ni] = b2p[vt0 * 128 + wc + ni * 16 + fr];
  {
    const unsigned short* base = Wb + (size_t)vt0 * 128 * 256;
#pragma unroll
    for (int i = 0; i < 8; i++) {
      const int slot = tid + i * 512;
      const int r = slot >> 5, kcp = slot & 31;
      const int kc = (kcp & 24) | ((kcp ^ r) & 7);
      stage16(base + (size_t)r * 256 + kc * 8, &sB[0][slot * 8]);
    }
  }

  for (int j = 0; j < nt; j++) {
#pragma unroll
    for (int ni = 0; ni < 4; ni++) bias_cur[ni] = bias_nxt[ni];
    if (j + 1 < nt) {
      const int vt = vt0 + j + 1;
#pragma unroll
      for (int ni = 0; ni < 4; ni++)     // bias loads BEFORE stages: vmcnt(8) is
        bias_nxt[ni] = b2p[vt * 128 + wc + ni * 16 + fr];   // correct either order
      const unsigned short* base = Wb + (size_t)vt * 128 * 256;
      unsigned short* dst = &sB[(j + 1) & 1][0];
#pragma unroll
      for (int i = 0; i < 8; i++) {
        const int slot = tid + i * 512;
        const int r = slot >> 5, kcp = slot & 31;
        const int kc = (kcp & 24) | ((kcp ^ r) & 7);
        stage16(base + (size_t)r * 256 + kc * 8, dst + slot * 8);
      }
      asm volatile("s_waitcnt vmcnt(8)" ::: "memory");  // tile j's stages drained
    } else {
      asm volatile("s_waitcnt vmcnt(0)" ::: "memory");
    }
    asm volatile("s_barrier" ::: "memory");             // buf[j&1] ready everywhere

    const unsigned short* bb = &sB[j & 1][0];
    floatx4 acc[2][4] = {};
#pragma unroll
    for (int ks = 0; ks < 8; ks++) {
      bf16x8 bv[4];
#pragma unroll
      for (int ni = 0; ni < 4; ni++) {
        const int r = wc + ni * 16 + fr;
        const int kc = ks * 4 + fq;
        const int slot = (r << 5) | (kc & 24) | ((kc ^ r) & 7);
        bv[ni] = *reinterpret_cast<const bf16x8*>(&bb[slot * 8]);
      }
#pragma unroll
      for (int mi = 0; mi < 2; mi++)
#pragma unroll
        for (int ni = 0; ni < 4; ni++)
          acc[mi][ni] = __builtin_amdgcn_mfma_f32_16x16x32_bf16(af[mi][ks], bv[ni], acc[mi][ni], 0, 0, 0);
    }
    // epilogue: accumulate sum of exp locally
#pragma unroll
    for (int mi = 0; mi < 2; mi++)
#pragma unroll
      for (int r = 0; r < 4; r++) {
        float s = sacc[mi][r];
#pragma unroll
        for (int ni = 0; ni < 4; ni++)
          s += __expf(acc[mi][ni][r] + bias_cur[ni]);
        sacc[mi][r] = s;
      }
    // all waves done computing on buf[j&1] before iter j+1 restages it.
    // raw barrier: this wave's ds_reads were already consumed by MFMAs.
    asm volatile("s_barrier" ::: "memory");
  }

  // final reduction: sum across the 16 fr lanes, one atomic per row
#pragma unroll
  for (int mi = 0; mi < 2; mi++)
#pragma unroll
    for (int r = 0; r < 4; r++) {
      float s = sacc[mi][r];
      s += __shfl_xor(s, 1);
      s += __shfl_xor(s, 2);
      s += __shfl_xor(s, 4);
      s += __shfl_xor(s, 8);
      if (fr == 0)
        atomicAdd(&lse_sum[mtile + wr + mi * 16 + fq * 4 + r], s);
    }
}

// ---- focal loss over T tags: one wave per tag-group ----
__global__ __launch_bounds__(256) void loss_k(
    const unsigned short* __restrict__ xbf, const float* __restrict__ W2,
    const float* __restrict__ b2, const int* __restrict__ tsid,
    const int* __restrict__ tags, const float* __restrict__ lse_sum,
    float* __restrict__ loss_acc) {
  const int lane = threadIdx.x & 63;
  const int gw = (int)(blockIdx.x * 256 + threadIdx.x) >> 6;
  const int nw = (int)(gridDim.x * 256) >> 6;
  float total = 0.f;
  for (int t = gw; t < T_; t += nw) {
    const int sid = tsid[t];
    const int v   = tags[t];
    const unsigned short* xr = xbf + (size_t)sid * L_;
    const float* w2r = W2 + (size_t)v * L_;
    float d = 0.f;
#pragma unroll
    for (int q = 0; q < 4; q++) {
      const int j = lane * 4 + q;
      d += bf2f(xr[j]) * w2r[j];
    }
#pragma unroll
    for (int m = 1; m < 64; m <<= 1) d += __shfl_xor(d, m);
    const float lp  = d + b2[v] - logf(lse_sum[sid]);
    const float pos = __expf(lp);
    total += (pos - 1.f) * lp;   // == -(1-pos)^1 * lp
  }
  if (lane == 0) atomicAdd(loss_acc, total);
}

__global__ void final_k(const float* __restrict__ loss_acc, float* __restrict__ out) {
  if (threadIdx.x == 0) out[0] = loss_acc[0] / (8192.0f + 1e-5f);
}

// ---- host launcher ----
extern "C" void kernel_launch(void* const* d_in, const int* in_sizes, int n_in,
                              void* d_out, int out_size, void* d_ws, size_t ws_size,
                              hipStream_t stream) {
  const float* hidden = (const float*)d_in[0];
  const float* W1     = (const float*)d_in[1];
  const float* b1     = (const float*)d_in[2];
  const float* W2     = (const float*)d_in[3];
  const float* b2     = (const float*)d_in[4];
  const int* sbid = (const int*)d_in[5];
  const int* sbeg = (const int*)d_in[6];
  const int* send = (const int*)d_in[7];
  const int* tsid = (const int*)d_in[8];
  const int* tags = (const int*)d_in[9];
  float* out = (float*)d_out;

  char* ws = (char*)d_ws;
  unsigned short* featbf = (unsigned short*)(ws);              //  8,388,608 B
  unsigned short* xbf    = (unsigned short*)(ws + 8388608);    //  2,097,152 B
  unsigned short* w1bf   = (unsigned short*)(ws + 10485760);   //    524,288 B
  unsigned short* w2bf   = (unsigned short*)(ws + 11010048);   // 25,624,576 B
  float* b2p  = (float*)(ws + 36634624);                       //    200,192 B
  float* lse  = (float*)(ws + 36834816);                       //  16,384 B + 4 (loss acc at lse[N_])
  float* lacc = lse + N_;

  gather_k<<<dim3(N_), dim3(256), 0, stream>>>(hidden, sbid, sbeg, send, featbf, lse);
  convert_k<<<dim3(4096), dim3(256), 0, stream>>>(W1, W2, b2, w1bf, w2bf, b2p);
  gemm1_k<<<dim3(256), dim3(256), 0, stream>>>(featbf, w1bf, b1, xbf);
  gemm2_k<<<dim3(256), dim3(512), 0, stream>>>(xbf, w2bf, b2p, lse);
  loss_k<<<dim3(256), dim3(256), 0, stream>>>(xbf, W2, b2, tsid, tags, lse, lacc);
  final_k<<<dim3(1), dim3(64), 0, stream>>>(lacc, out);
}

// Round 4
// 362.935 us; speedup vs baseline: 1.2681x; 1.0093x over previous
//
#include <hip/hip_runtime.h>

// ---- problem constants ----
#define S_    2048
#define B_    16
#define H2_   1024
#define H_    512
#define N_    4096
#define T_    8192
#define L_    256
#define V_    50000
#define VPAD_ 50048   // 391 * 128

typedef float  floatx4 __attribute__((ext_vector_type(4)));
typedef __bf16 bf16x8  __attribute__((ext_vector_type(8)));

__device__ inline unsigned short f2bf(float f) {
  unsigned u = __builtin_bit_cast(unsigned, f);
  unsigned r = u + 0x7fffu + ((u >> 16) & 1u);   // RNE
  return (unsigned short)(r >> 16);
}
__device__ inline float bf2f(unsigned short s) {
  unsigned u = ((unsigned)s) << 16;
  return __builtin_bit_cast(float, u);
}

// async global->LDS, 16B per lane; LDS dest = wave-uniform base + lane*16
// (global SOURCE address may be per-lane scattered — only the LDS dest is fixed)
__device__ inline void stage16(const unsigned short* g, unsigned short* l) {
  __builtin_amdgcn_global_load_lds(
      (const __attribute__((address_space(1))) void*)g,
      (__attribute__((address_space(3))) void*)l, 16, 0, 0);
}

// ---- gather span features -> bf16 [N_][H2_]; also zeroes lse/loss/ticket ----
__global__ __launch_bounds__(256) void gather_k(
    const float* __restrict__ hidden, const int* __restrict__ sbid,
    const int* __restrict__ sbeg, const int* __restrict__ send,
    unsigned short* __restrict__ featbf, float* __restrict__ lse) {
  const int n = blockIdx.x;
  const int t = threadIdx.x;
  if (t == 0) lse[n] = 0.f;
  if (n == 0 && t == 1) lse[N_] = 0.f;                     // loss accumulator
  if (n == 0 && t == 2) ((unsigned*)lse)[N_ + 1] = 0u;     // ticket counter
  const int bid = sbid[n];
  int r = sbeg[n] - 1; if (r < 0) r += S_;     // (span_begin-1) mod S
  const int e = send[n];
  const size_t fbase = (size_t)r * (B_ * H2_) + (size_t)bid * H2_;
  const size_t bbase = (size_t)e * (B_ * H2_) + (size_t)bid * H2_;
  const int c = t * 4;                    // element index 0..1023 (wave-uniform branch)
  const float4 v = (t < 128) ? *reinterpret_cast<const float4*>(hidden + fbase + c)
                             : *reinterpret_cast<const float4*>(hidden + bbase + c);
  unsigned short o[4];
  o[0] = f2bf(v.x); o[1] = f2bf(v.y); o[2] = f2bf(v.z); o[3] = f2bf(v.w);
  *reinterpret_cast<unsigned long long*>(featbf + (size_t)n * H2_ + c) =
      *reinterpret_cast<unsigned long long*>(o);
}

// ---- convert W1, W2 (padded), b2 (padded) ----
__global__ __launch_bounds__(256) void convert_k(
    const float* __restrict__ W1, const float* __restrict__ W2,
    const float* __restrict__ b2, unsigned short* __restrict__ w1b,
    unsigned short* __restrict__ w2b, float* __restrict__ b2p) {
  const int gid = blockIdx.x * 256 + threadIdx.x;
  const int gstride = gridDim.x * 256;
  for (long j = (long)gid * 8; j < (long)VPAD_ * 256; j += (long)gstride * 8) {
    int row = (int)(j >> 8);
    unsigned short o[8];
    if (row < V_) {
#pragma unroll
      for (int q = 0; q < 8; q++) o[q] = f2bf(W2[j + q]);
    } else {
#pragma unroll
      for (int q = 0; q < 8; q++) o[q] = 0;
    }
    *reinterpret_cast<ulonglong2*>(w2b + j) = *reinterpret_cast<ulonglong2*>(o);
  }
  for (int j = gid; j < L_ * H2_; j += gstride) w1b[j] = f2bf(W1[j]);
  for (int j = gid; j < VPAD_; j += gstride) b2p[j] = (j < V_) ? b2[j] : -1e30f;
}

// ---- GEMM1: x = tanh(feat @ W1^T + b1), 64x64 tiles, 256 blocks ----
__global__ __launch_bounds__(256) void gemm1_k(
    const unsigned short* __restrict__ A,   // featbf [N_][H2_]
    const unsigned short* __restrict__ Bw,  // w1bf  [L_][H2_]
    const float* __restrict__ b1,
    unsigned short* __restrict__ xbf) {     // [N_][L_]
  __shared__ __align__(16) unsigned short sA[64 * 64];
  __shared__ __align__(16) unsigned short sB[64 * 64];
  const int tid   = threadIdx.x;
  const int mtile = (int)(blockIdx.x >> 2) * 64;
  const int ntile = (int)(blockIdx.x & 3) * 64;
  const int lane = tid & 63, wave = tid >> 6;
  const int wr = (wave & 1) * 32, wc = (wave >> 1) * 32;
  const int fr = lane & 15, fq = lane >> 4;
  floatx4 acc[2][2] = {};
  for (int k0 = 0; k0 < H2_; k0 += 64) {
#pragma unroll
    for (int i = 0; i < 2; i++) {
      const int slot = tid + i * 256;          // 0..511 (16B chunks)
      const int r = slot >> 3, cc = slot & 7;
      const int gk = cc ^ (r & 7);             // bank swizzle on global source
      stage16(A  + (size_t)(mtile + r) * H2_ + k0 + gk * 8, &sA[slot * 8]);
      stage16(Bw + (size_t)(ntile + r) * H2_ + k0 + gk * 8, &sB[slot * 8]);
    }
    __syncthreads();
#pragma unroll
    for (int ks = 0; ks < 2; ks++) {
      bf16x8 av[2], bv[2];
#pragma unroll
      for (int mi = 0; mi < 2; mi++) {
        const int r = wr + mi * 16 + fr, kc = ks * 4 + fq;
        av[mi] = *reinterpret_cast<const bf16x8*>(&sA[(r * 8 + (kc ^ (r & 7))) * 8]);
      }
#pragma unroll
      for (int ni = 0; ni < 2; ni++) {
        const int r = wc + ni * 16 + fr, kc = ks * 4 + fq;
        bv[ni] = *reinterpret_cast<const bf16x8*>(&sB[(r * 8 + (kc ^ (r & 7))) * 8]);
      }
#pragma unroll
      for (int mi = 0; mi < 2; mi++)
#pragma unroll
        for (int ni = 0; ni < 2; ni++)
          acc[mi][ni] = __builtin_amdgcn_mfma_f32_16x16x32_bf16(av[mi], bv[ni], acc[mi][ni], 0, 0, 0);
    }
    __syncthreads();
  }
#pragma unroll
  for (int ni = 0; ni < 2; ni++) {
    const int col = ntile + wc + ni * 16 + fr;
    const float bias = b1[col];
#pragma unroll
    for (int mi = 0; mi < 2; mi++)
#pragma unroll
      for (int r = 0; r < 4; r++) {
        const int row = mtile + wr + mi * 16 + fq * 4 + r;
        xbf[(size_t)row * L_ + col] = f2bf(tanhf(acc[mi][ni][r] + bias));
      }
  }
}

// ---- GEMM2 + online sum-of-exp ----
// 512 threads (8 waves, 2/SIMD). Wave grid 2m x 4n: M_w=64 rows per wave ->
// af[4][8] (128 VGPR) register-resident, only ni=2 B-frag reads per ks.
// B double-buffered 64KB LDS, prefetch guarded by s_waitcnt vmcnt(10)
// (= bias(2) + stages(8) newest in flight). Raw s_barrier, no drain.
// Grid: 8 strips x 32 mtiles = 256 blocks, 1 block/CU.
__global__ __launch_bounds__(512, 2) void gemm2_k(
    const unsigned short* __restrict__ X,   // xbf [N_][L_]
    const unsigned short* __restrict__ Wb,  // w2bf [VPAD_][L_]
    const float* __restrict__ b2p,          // [VPAD_] (-1e30 on pad)
    float* __restrict__ lse_sum) {          // [N_], pre-zeroed
  __shared__ __align__(16) unsigned short sB[2][128 * 256];  // 2 x 64KB
  const int tid   = threadIdx.x;
  const int mtile = ((int)blockIdx.x & 31) * 128;
  const int strip = (int)blockIdx.x >> 5;                    // 0..7
  const int vt0   = strip * 49;
  const int nt    = (strip < 7) ? 49 : 48;                   // 7*49+48=391
  const int lane = tid & 63, wave = tid >> 6;
  const int wr = (wave & 1) * 64;                            // 2 m-waves x 64 rows
  const int wc = (wave >> 1) * 32;                           // 4 n-waves x 32 cols
  const int fr = lane & 15, fq = lane >> 4;

  // ---- stage A tile (swizzled) into sB[0], pull frags to registers ----
#pragma unroll
  for (int i = 0; i < 8; i++) {
    const int slot = tid + i * 512;           // 0..4095 (16B chunks)
    const int r = slot >> 5, kcp = slot & 31;
    const int kc = (kcp & 24) | ((kcp ^ r) & 7);
    stage16(X + (size_t)(mtile + r) * 256 + kc * 8, &sB[0][slot * 8]);
  }
  __syncthreads();
  bf16x8 af[4][8];
#pragma unroll
  for (int mi = 0; mi < 4; mi++)
#pragma unroll
    for (int ks = 0; ks < 8; ks++) {
      const int r = wr + mi * 16 + fr;
      const int kc = ks * 4 + fq;
      const int slot = (r << 5) | (kc & 24) | ((kc ^ r) & 7);
      af[mi][ks] = *reinterpret_cast<const bf16x8*>(&sB[0][slot * 8]);
    }
  __syncthreads();   // all waves done with A before buf0 is reused for B

  float sacc[4][4];
#pragma unroll
  for (int mi = 0; mi < 4; mi++)
#pragma unroll
    for (int r = 0; r < 4; r++) sacc[mi][r] = 0.f;

  // prologue: bias + stage for tile 0 (into buf0); bias loads FIRST
  float bias_nxt[2], bias_cur[2];
#pragma unroll
  for (int ni = 0; ni < 2; ni++)
    bias_nxt[ni] = b2p[vt0 * 128 + wc + ni * 16 + fr];
  {
    const unsigned short* base = Wb + (size_t)vt0 * 128 * 256;
#pragma unroll
    for (int i = 0; i < 8; i++) {
      const int slot = tid + i * 512;
      const int r = slot >> 5, kcp = slot & 31;
      const int kc = (kcp & 24) | ((kcp ^ r) & 7);
      stage16(base + (size_t)r * 256 + kc * 8, &sB[0][slot * 8]);
    }
  }

  for (int j = 0; j < nt; j++) {
#pragma unroll
    for (int ni = 0; ni < 2; ni++) bias_cur[ni] = bias_nxt[ni];
    if (j + 1 < nt) {
      const int vt = vt0 + j + 1;
#pragma unroll
      for (int ni = 0; ni < 2; ni++)
        bias_nxt[ni] = b2p[vt * 128 + wc + ni * 16 + fr];
      const unsigned short* base = Wb + (size_t)vt * 128 * 256;
      unsigned short* dst = &sB[(j + 1) & 1][0];
#pragma unroll
      for (int i = 0; i < 8; i++) {
        const int slot = tid + i * 512;
        const int r = slot >> 5, kcp = slot & 31;
        const int kc = (kcp & 24) | ((kcp ^ r) & 7);
        stage16(base + (size_t)r * 256 + kc * 8, dst + slot * 8);
      }
      // keep only the 10 newest (bias j+1: 2, stages j+1: 8) => stages j drained
      asm volatile("s_waitcnt vmcnt(10)" ::: "memory");
    } else {
      asm volatile("s_waitcnt vmcnt(0)" ::: "memory");
    }
    asm volatile("s_barrier" ::: "memory");             // buf[j&1] ready everywhere

    const unsigned short* bb = &sB[j & 1][0];
    floatx4 acc[4][2] = {};
#pragma unroll
    for (int ks = 0; ks < 8; ks++) {
      bf16x8 bv[2];
#pragma unroll
      for (int ni = 0; ni < 2; ni++) {
        const int r = wc + ni * 16 + fr;
        const int kc = ks * 4 + fq;
        const int slot = (r << 5) | (kc & 24) | ((kc ^ r) & 7);
        bv[ni] = *reinterpret_cast<const bf16x8*>(&bb[slot * 8]);
      }
#pragma unroll
      for (int mi = 0; mi < 4; mi++)
#pragma unroll
        for (int ni = 0; ni < 2; ni++)
          acc[mi][ni] = __builtin_amdgcn_mfma_f32_16x16x32_bf16(af[mi][ks], bv[ni], acc[mi][ni], 0, 0, 0);
    }
    // epilogue: accumulate sum of exp locally
#pragma unroll
    for (int mi = 0; mi < 4; mi++)
#pragma unroll
      for (int r = 0; r < 4; r++) {
        float s = sacc[mi][r];
#pragma unroll
        for (int ni = 0; ni < 2; ni++)
          s += __expf(acc[mi][ni][r] + bias_cur[ni]);
        sacc[mi][r] = s;
      }
    // all waves done computing on buf[j&1] before iter j+1 restages it.
    asm volatile("s_barrier" ::: "memory");
  }

  // final reduction: sum across the 16 fr lanes, one atomic per row
#pragma unroll
  for (int mi = 0; mi < 4; mi++)
#pragma unroll
    for (int r = 0; r < 4; r++) {
      float s = sacc[mi][r];
      s += __shfl_xor(s, 1);
      s += __shfl_xor(s, 2);
      s += __shfl_xor(s, 4);
      s += __shfl_xor(s, 8);
      if (fr == 0)
        atomicAdd(&lse_sum[mtile + wr + mi * 16 + fq * 4 + r], s);
    }
}

// ---- focal loss over T tags + fused finalization (ticket) ----
__global__ __launch_bounds__(256) void loss_k(
    const unsigned short* __restrict__ xbf, const float* __restrict__ W2,
    const float* __restrict__ b2, const int* __restrict__ tsid,
    const int* __restrict__ tags, const float* __restrict__ lse_sum,
    float* __restrict__ loss_acc, unsigned* __restrict__ ticket,
    float* __restrict__ out) {
  const int lane = threadIdx.x & 63;
  const int gw = (int)(blockIdx.x * 256 + threadIdx.x) >> 6;
  const int nw = (int)(gridDim.x * 256) >> 6;
  float total = 0.f;
  for (int t = gw; t < T_; t += nw) {
    const int sid = tsid[t];
    const int v   = tags[t];
    const unsigned short* xr = xbf + (size_t)sid * L_;
    const float* w2r = W2 + (size_t)v * L_;
    float d = 0.f;
#pragma unroll
    for (int q = 0; q < 4; q++) {
      const int j = lane * 4 + q;
      d += bf2f(xr[j]) * w2r[j];
    }
#pragma unroll
    for (int m = 1; m < 64; m <<= 1) d += __shfl_xor(d, m);
    const float lp  = d + b2[v] - logf(lse_sum[sid]);
    const float pos = __expf(lp);
    total += (pos - 1.f) * lp;   // == -(1-pos)^1 * lp
  }
  if (lane == 0) atomicAdd(loss_acc, total);
  __syncthreads();
  __threadfence();
  if (threadIdx.x == 0) {
    const unsigned t = atomicAdd(ticket, 1u);
    if (t == (unsigned)gridDim.x - 1u) {
      const float v = atomicAdd(loss_acc, 0.0f);   // device-scope read
      out[0] = v / (8192.0f + 1e-5f);
    }
  }
}

// ---- host launcher ----
extern "C" void kernel_launch(void* const* d_in, const int* in_sizes, int n_in,
                              void* d_out, int out_size, void* d_ws, size_t ws_size,
                              hipStream_t stream) {
  const float* hidden = (const float*)d_in[0];
  const float* W1     = (const float*)d_in[1];
  const float* b1     = (const float*)d_in[2];
  const float* W2     = (const float*)d_in[3];
  const float* b2     = (const float*)d_in[4];
  const int* sbid = (const int*)d_in[5];
  const int* sbeg = (const int*)d_in[6];
  const int* send = (const int*)d_in[7];
  const int* tsid = (const int*)d_in[8];
  const int* tags = (const int*)d_in[9];
  float* out = (float*)d_out;

  char* ws = (char*)d_ws;
  unsigned short* featbf = (unsigned short*)(ws);              //  8,388,608 B
  unsigned short* xbf    = (unsigned short*)(ws + 8388608);    //  2,097,152 B
  unsigned short* w1bf   = (unsigned short*)(ws + 10485760);   //    524,288 B
  unsigned short* w2bf   = (unsigned short*)(ws + 11010048);   // 25,624,576 B
  float* b2p  = (float*)(ws + 36634624);                       //    200,192 B
  float* lse  = (float*)(ws + 36834816);                       //  N_ floats + lacc + ticket
  float* lacc = lse + N_;
  unsigned* ticket = (unsigned*)(lse + N_ + 1);

  gather_k<<<dim3(N_), dim3(256), 0, stream>>>(hidden, sbid, sbeg, send, featbf, lse);
  convert_k<<<dim3(4096), dim3(256), 0, stream>>>(W1, W2, b2, w1bf, w2bf, b2p);
  gemm1_k<<<dim3(256), dim3(256), 0, stream>>>(featbf, w1bf, b1, xbf);
  gemm2_k<<<dim3(256), dim3(512), 0, stream>>>(xbf, w2bf, b2p, lse);
  loss_k<<<dim3(256), dim3(256), 0, stream>>>(xbf, W2, b2, tsid, tags, lse, lacc, ticket, out);
}

// Round 5
// 352.612 us; speedup vs baseline: 1.3052x; 1.0293x over previous
//
#include <hip/hip_runtime.h>
#include <hip/hip_fp8.h>

// ---- problem constants ----
#define S_    2048
#define B_    16
#define H2_   1024
#define H_    512
#define N_    4096
#define T_    8192
#define L_    256
#define V_    50000
#define VPAD_ 50048   // 391 * 128

typedef float  floatx4 __attribute__((ext_vector_type(4)));
typedef __bf16 bf16x8  __attribute__((ext_vector_type(8)));

__device__ inline unsigned short f2bf(float f) {
  unsigned u = __builtin_bit_cast(unsigned, f);
  unsigned r = u + 0x7fffu + ((u >> 16) & 1u);   // RNE
  return (unsigned short)(r >> 16);
}
__device__ inline float bf2f(unsigned short s) {
  unsigned u = ((unsigned)s) << 16;
  return __builtin_bit_cast(float, u);
}
__device__ inline unsigned char f2fp8(float f) {
  return (unsigned char)__hip_cvt_float_to_fp8(f, __HIP_SATFINITE, __HIP_E4M3);
}

// async global->LDS, 16B per lane; LDS dest = wave-uniform base + lane*16
// (global SOURCE address may be per-lane scattered — only the LDS dest is fixed)
__device__ inline void stage16(const void* g, void* l) {
  __builtin_amdgcn_global_load_lds(
      (const __attribute__((address_space(1))) void*)g,
      (__attribute__((address_space(3))) void*)l, 16, 0, 0);
}

// ---- gather span features -> bf16 [N_][H2_]; also zeroes lse/loss/ticket ----
__global__ __launch_bounds__(256) void gather_k(
    const float* __restrict__ hidden, const int* __restrict__ sbid,
    const int* __restrict__ sbeg, const int* __restrict__ send,
    unsigned short* __restrict__ featbf, float* __restrict__ lse) {
  const int n = blockIdx.x;
  const int t = threadIdx.x;
  if (t == 0) lse[n] = 0.f;
  if (n == 0 && t == 1) lse[N_] = 0.f;                     // loss accumulator
  if (n == 0 && t == 2) ((unsigned*)lse)[N_ + 1] = 0u;     // ticket counter
  const int bid = sbid[n];
  int r = sbeg[n] - 1; if (r < 0) r += S_;     // (span_begin-1) mod S
  const int e = send[n];
  const size_t fbase = (size_t)r * (B_ * H2_) + (size_t)bid * H2_;
  const size_t bbase = (size_t)e * (B_ * H2_) + (size_t)bid * H2_;
  const int c = t * 4;                    // element index 0..1023 (wave-uniform branch)
  const float4 v = (t < 128) ? *reinterpret_cast<const float4*>(hidden + fbase + c)
                             : *reinterpret_cast<const float4*>(hidden + bbase + c);
  unsigned short o[4];
  o[0] = f2bf(v.x); o[1] = f2bf(v.y); o[2] = f2bf(v.z); o[3] = f2bf(v.w);
  *reinterpret_cast<unsigned long long*>(featbf + (size_t)n * H2_ + c) =
      *reinterpret_cast<unsigned long long*>(o);
}

// ---- convert W1 (bf16), W2 (fp8 e4m3, padded), eb = exp(b2) (padded 0) ----
__global__ __launch_bounds__(256) void convert_k(
    const float* __restrict__ W1, const float* __restrict__ W2,
    const float* __restrict__ b2, unsigned short* __restrict__ w1b,
    unsigned char* __restrict__ w2f8, float* __restrict__ ebp) {
  const int gid = blockIdx.x * 256 + threadIdx.x;
  const int gstride = gridDim.x * 256;
  for (long j = (long)gid * 8; j < (long)VPAD_ * 256; j += (long)gstride * 8) {
    int row = (int)(j >> 8);
    unsigned char o[8];
    if (row < V_) {
#pragma unroll
      for (int q = 0; q < 8; q++) o[q] = f2fp8(W2[j + q]);
    } else {
#pragma unroll
      for (int q = 0; q < 8; q++) o[q] = 0;
    }
    *reinterpret_cast<unsigned long long*>(w2f8 + j) =
        *reinterpret_cast<unsigned long long*>(o);
  }
  for (int j = gid; j < L_ * H2_; j += gstride) w1b[j] = f2bf(W1[j]);
  for (int j = gid; j < VPAD_; j += gstride) ebp[j] = (j < V_) ? __expf(b2[j]) : 0.f;
}

// ---- GEMM1: x = tanh(feat @ W1^T + b1) -> xbf (bf16, loss) + xf8 (fp8, gemm2) ----
__global__ __launch_bounds__(256) void gemm1_k(
    const unsigned short* __restrict__ A,   // featbf [N_][H2_]
    const unsigned short* __restrict__ Bw,  // w1bf  [L_][H2_]
    const float* __restrict__ b1,
    unsigned short* __restrict__ xbf,       // [N_][L_]
    unsigned char* __restrict__ xf8) {      // [N_][L_]
  __shared__ __align__(16) unsigned short sA[64 * 64];
  __shared__ __align__(16) unsigned short sB[64 * 64];
  const int tid   = threadIdx.x;
  const int mtile = (int)(blockIdx.x >> 2) * 64;
  const int ntile = (int)(blockIdx.x & 3) * 64;
  const int lane = tid & 63, wave = tid >> 6;
  const int wr = (wave & 1) * 32, wc = (wave >> 1) * 32;
  const int fr = lane & 15, fq = lane >> 4;
  floatx4 acc[2][2] = {};
  for (int k0 = 0; k0 < H2_; k0 += 64) {
#pragma unroll
    for (int i = 0; i < 2; i++) {
      const int slot = tid + i * 256;          // 0..511 (16B chunks)
      const int r = slot >> 3, cc = slot & 7;
      const int gk = cc ^ (r & 7);             // bank swizzle on global source
      stage16(A  + (size_t)(mtile + r) * H2_ + k0 + gk * 8, &sA[slot * 8]);
      stage16(Bw + (size_t)(ntile + r) * H2_ + k0 + gk * 8, &sB[slot * 8]);
    }
    __syncthreads();
#pragma unroll
    for (int ks = 0; ks < 2; ks++) {
      bf16x8 av[2], bv[2];
#pragma unroll
      for (int mi = 0; mi < 2; mi++) {
        const int r = wr + mi * 16 + fr, kc = ks * 4 + fq;
        av[mi] = *reinterpret_cast<const bf16x8*>(&sA[(r * 8 + (kc ^ (r & 7))) * 8]);
      }
#pragma unroll
      for (int ni = 0; ni < 2; ni++) {
        const int r = wc + ni * 16 + fr, kc = ks * 4 + fq;
        bv[ni] = *reinterpret_cast<const bf16x8*>(&sB[(r * 8 + (kc ^ (r & 7))) * 8]);
      }
#pragma unroll
      for (int mi = 0; mi < 2; mi++)
#pragma unroll
        for (int ni = 0; ni < 2; ni++)
          acc[mi][ni] = __builtin_amdgcn_mfma_f32_16x16x32_bf16(av[mi], bv[ni], acc[mi][ni], 0, 0, 0);
    }
    __syncthreads();
  }
#pragma unroll
  for (int ni = 0; ni < 2; ni++) {
    const int col = ntile + wc + ni * 16 + fr;
    const float bias = b1[col];
#pragma unroll
    for (int mi = 0; mi < 2; mi++)
#pragma unroll
      for (int r = 0; r < 4; r++) {
        const int row = mtile + wr + mi * 16 + fq * 4 + r;
        const float t = tanhf(acc[mi][ni][r] + bias);
        xbf[(size_t)row * L_ + col] = f2bf(t);
        xf8[(size_t)row * L_ + col] = f2fp8(t);
      }
  }
}

// ---- GEMM2 (fp8) + online sum-of-exp ----
// 512 threads (8 waves), 2 blocks/CU (2x32KB LDS, <=128 VGPR target).
// A tile register-resident as fp8 i64 frags. B double-buffered 32KB tiles,
// staged via global_load_lds AFTER the per-tile barrier, consumed one full
// tile later (no same-iteration drain). XOR-16B-chunk swizzle -> conflict-free
// ds_read_b64 frag reads. XCD-aware mapping: strip = blk&15 -> each XCD
// touches ~2 strips of W2. Epilogue: s = fma(eb, exp(acc), s); eb=0 kills pad.
// Grid: 16 strips x 32 mtiles = 512 blocks.
__global__ __launch_bounds__(512, 2) void gemm2_k(
    const unsigned char* __restrict__ X8,   // xf8 [N_][256]
    const unsigned char* __restrict__ W8,   // w2f8 [VPAD_][256]
    const float* __restrict__ ebp,          // exp(b2), pad = 0
    float* __restrict__ lse_sum) {          // [N_], pre-zeroed
  __shared__ __align__(16) unsigned char sB[2][32768];
  const int tid   = threadIdx.x;
  const int mtile = ((int)blockIdx.x >> 4) * 128;
  const int strip = (int)blockIdx.x & 15;
  const int vt0   = (strip < 7) ? strip * 25 : 175 + (strip - 7) * 24;
  const int nt    = (strip < 7) ? 25 : 24;                 // 7*25+9*24 = 391
  const int lane = tid & 63, wave = tid >> 6;
  const int wr = (wave & 1) * 64;                          // 2 m-waves x 64 rows
  const int wc = (wave >> 1) * 32;                         // 4 n-waves x 32 cols
  const int fr = lane & 15, fq = lane >> 4;

  // ---- stage A tile (32KB, swizzled) into buf0, pull frags to registers ----
#pragma unroll
  for (int i = 0; i < 4; i++) {
    const int slot = tid + i * 512;           // 0..2047 (16B chunks)
    const int r = slot >> 4, c = slot & 15;
    stage16(X8 + (size_t)(mtile + r) * 256 + ((c ^ (r & 15)) << 4), &sB[0][slot << 4]);
  }
  __syncthreads();
  long af[4][8];
#pragma unroll
  for (int mi = 0; mi < 4; mi++)
#pragma unroll
    for (int ks = 0; ks < 8; ks++) {
      const int r = wr + mi * 16 + fr;
      const int kb = ks * 32 + fq * 8;
      const int c = kb >> 4, o = kb & 15;
      af[mi][ks] = *reinterpret_cast<const long*>(
          &sB[0][(r << 8) + ((c ^ (r & 15)) << 4) + o]);
    }
  __syncthreads();   // all waves done with A before buf0 is reused for B

  float sacc[4][4];
#pragma unroll
  for (int mi = 0; mi < 4; mi++)
#pragma unroll
    for (int r = 0; r < 4; r++) sacc[mi][r] = 0.f;

  // prologue: eb + stage for tile 0 (into buf0)
  float eb_cur[2], eb_nxt[2];
#pragma unroll
  for (int ni = 0; ni < 2; ni++)
    eb_nxt[ni] = ebp[vt0 * 128 + wc + ni * 16 + fr];
  {
    const unsigned char* base = W8 + (size_t)vt0 * 128 * 256;
#pragma unroll
    for (int i = 0; i < 4; i++) {
      const int slot = tid + i * 512;
      const int r = slot >> 4, c = slot & 15;
      stage16(base + ((size_t)r << 8) + ((c ^ (r & 15)) << 4), &sB[0][slot << 4]);
    }
  }

  for (int j = 0; j < nt; j++) {
#pragma unroll
    for (int ni = 0; ni < 2; ni++) eb_cur[ni] = eb_nxt[ni];
    // barrier first: (a) tile j's stages drained (vmcnt0 in syncthreads),
    // (b) every wave finished reading buf[(j+1)&1] (tile j-1) -> safe restage.
    __syncthreads();
    if (j + 1 < nt) {
      const int vt = vt0 + j + 1;
#pragma unroll
      for (int ni = 0; ni < 2; ni++)
        eb_nxt[ni] = ebp[vt * 128 + wc + ni * 16 + fr];
      const unsigned char* base = W8 + (size_t)vt * 128 * 256;
      unsigned char* dst = &sB[(j + 1) & 1][0];
#pragma unroll
      for (int i = 0; i < 4; i++) {
        const int slot = tid + i * 512;
        const int r = slot >> 4, c = slot & 15;
        stage16(base + ((size_t)r << 8) + ((c ^ (r & 15)) << 4), dst + (slot << 4));
      }
    }

    const unsigned char* bb = &sB[j & 1][0];
    floatx4 acc[4][2] = {};
#pragma unroll
    for (int ks = 0; ks < 8; ks++) {
      long bv[2];
#pragma unroll
      for (int ni = 0; ni < 2; ni++) {
        const int r = wc + ni * 16 + fr;
        const int kb = ks * 32 + fq * 8;
        const int c = kb >> 4, o = kb & 15;
        bv[ni] = *reinterpret_cast<const long*>(
            &bb[(r << 8) + ((c ^ (r & 15)) << 4) + o]);
      }
#pragma unroll
      for (int mi = 0; mi < 4; mi++)
#pragma unroll
        for (int ni = 0; ni < 2; ni++)
          acc[mi][ni] = __builtin_amdgcn_mfma_f32_16x16x32_fp8_fp8(
              af[mi][ks], bv[ni], acc[mi][ni], 0, 0, 0);
    }
    // epilogue: sacc += eb * exp(logit)
#pragma unroll
    for (int mi = 0; mi < 4; mi++)
#pragma unroll
      for (int r = 0; r < 4; r++) {
        float s = sacc[mi][r];
#pragma unroll
        for (int ni = 0; ni < 2; ni++)
          s = fmaf(eb_cur[ni], __expf(acc[mi][ni][r]), s);
        sacc[mi][r] = s;
      }
  }

  // final reduction: sum across the 16 fr lanes, one atomic per row
#pragma unroll
  for (int mi = 0; mi < 4; mi++)
#pragma unroll
    for (int r = 0; r < 4; r++) {
      float s = sacc[mi][r];
      s += __shfl_xor(s, 1);
      s += __shfl_xor(s, 2);
      s += __shfl_xor(s, 4);
      s += __shfl_xor(s, 8);
      if (fr == 0)
        atomicAdd(&lse_sum[mtile + wr + mi * 16 + fq * 4 + r], s);
    }
}

// ---- focal loss over T tags + fused finalization (ticket) ----
__global__ __launch_bounds__(256) void loss_k(
    const unsigned short* __restrict__ xbf, const float* __restrict__ W2,
    const float* __restrict__ b2, const int* __restrict__ tsid,
    const int* __restrict__ tags, const float* __restrict__ lse_sum,
    float* __restrict__ loss_acc, unsigned* __restrict__ ticket,
    float* __restrict__ out) {
  const int lane = threadIdx.x & 63;
  const int gw = (int)(blockIdx.x * 256 + threadIdx.x) >> 6;
  const int nw = (int)(gridDim.x * 256) >> 6;
  float total = 0.f;
  for (int t = gw; t < T_; t += nw) {
    const int sid = tsid[t];
    const int v   = tags[t];
    const unsigned short* xr = xbf + (size_t)sid * L_;
    const float* w2r = W2 + (size_t)v * L_;
    float d = 0.f;
#pragma unroll
    for (int q = 0; q < 4; q++) {
      const int j = lane * 4 + q;
      d += bf2f(xr[j]) * w2r[j];
    }
#pragma unroll
    for (int m = 1; m < 64; m <<= 1) d += __shfl_xor(d, m);
    const float lp  = d + b2[v] - logf(lse_sum[sid]);
    const float pos = __expf(lp);
    total += (pos - 1.f) * lp;   // == -(1-pos)^1 * lp
  }
  if (lane == 0) atomicAdd(loss_acc, total);
  __syncthreads();
  __threadfence();
  if (threadIdx.x == 0) {
    const unsigned t = atomicAdd(ticket, 1u);
    if (t == (unsigned)gridDim.x - 1u) {
      const float v = atomicAdd(loss_acc, 0.0f);   // device-scope read
      out[0] = v / (8192.0f + 1e-5f);
    }
  }
}

// ---- host launcher ----
extern "C" void kernel_launch(void* const* d_in, const int* in_sizes, int n_in,
                              void* d_out, int out_size, void* d_ws, size_t ws_size,
                              hipStream_t stream) {
  const float* hidden = (const float*)d_in[0];
  const float* W1     = (const float*)d_in[1];
  const float* b1     = (const float*)d_in[2];
  const float* W2     = (const float*)d_in[3];
  const float* b2     = (const float*)d_in[4];
  const int* sbid = (const int*)d_in[5];
  const int* sbeg = (const int*)d_in[6];
  const int* send = (const int*)d_in[7];
  const int* tsid = (const int*)d_in[8];
  const int* tags = (const int*)d_in[9];
  float* out = (float*)d_out;

  char* ws = (char*)d_ws;
  unsigned short* featbf = (unsigned short*)(ws);              //  8,388,608 B
  unsigned short* xbf    = (unsigned short*)(ws + 8388608);    //  2,097,152 B
  unsigned short* w1bf   = (unsigned short*)(ws + 10485760);   //    524,288 B
  unsigned char*  xf8    = (unsigned char*) (ws + 11010048);   //  1,048,576 B
  unsigned char*  w2f8   = (unsigned char*) (ws + 12058624);   // 12,812,288 B
  float* ebp  = (float*)(ws + 24870912);                       //    200,192 B
  float* lse  = (float*)(ws + 25071104);                       //  N_ floats + lacc + ticket
  float* lacc = lse + N_;
  unsigned* ticket = (unsigned*)(lse + N_ + 1);

  gather_k<<<dim3(N_), dim3(256), 0, stream>>>(hidden, sbid, sbeg, send, featbf, lse);
  convert_k<<<dim3(4096), dim3(256), 0, stream>>>(W1, W2, b2, w1bf, w2f8, ebp);
  gemm1_k<<<dim3(256), dim3(256), 0, stream>>>(featbf, w1bf, b1, xbf, xf8);
  gemm2_k<<<dim3(512), dim3(512), 0, stream>>>(xf8, w2f8, ebp, lse);
  loss_k<<<dim3(256), dim3(256), 0, stream>>>(xbf, W2, b2, tsid, tags, lse, lacc, ticket, out);
}